// Round 12
// baseline (495.552 us; speedup 1.0000x reference)
//
#include <hip/hip_runtime.h>
#include <stdint.h>
#include <stddef.h>

// ---------- types ----------
typedef __attribute__((ext_vector_type(4))) float  floatx4;
typedef __attribute__((ext_vector_type(8))) short  short8;   // 8 bf16 (MFMA A/B frag)
typedef __attribute__((ext_vector_type(4))) short  short4v;

__device__ __forceinline__ float bf2f(short s) {
  union { uint32_t u; float f; } v;
  v.u = ((uint32_t)(uint16_t)s) << 16;
  return v.f;
}
__device__ __forceinline__ short f2bf(float f) {
  union { float f; uint32_t u; } v; v.f = f;
  uint32_t r = v.u + 0x7fffu + ((v.u >> 16) & 1u);   // RNE
  return (short)(r >> 16);
}

__device__ __forceinline__ void async_cp16(const void* g, void* l) {
  __builtin_amdgcn_global_load_lds(
      (__attribute__((address_space(1))) void*)g,
      (__attribute__((address_space(3))) void*)l, 16, 0, 0);
}

// XOR-swizzle byte offset inside a [row][128B] LDS tile: spreads the 128B-row
// bank collision (guide G4: byte ^= (row&7)<<4), bijective per row, keeps 16B align.
__device__ __forceinline__ int swzb(int row, int bcol) {
  return ((row << 7) + bcol) ^ ((row & 7) << 4);
}

// ---------- fused weight transposes: fp32 (K x N) -> bf16 (N x K), 10 weights, 1 launch ----------
struct TransTable {
  const float* src[10];
  short*       dst[10];
  int K[10], N[10], base[10];   // base = first global tile id of entry
};
__global__ __launch_bounds__(256)
void transpose_all(TransTable tt)
{
  __shared__ short tile[32][33];
  int e = 0;
  #pragma unroll
  for (int i = 1; i < 10; i++) if ((int)blockIdx.x >= tt.base[i]) e = i;
  const int t = blockIdx.x - tt.base[e];
  const int N = tt.N[e], K = tt.K[e];
  const int ncols = N >> 5;
  const int n0 = (t % ncols) << 5, k0 = (t / ncols) << 5;
  const float* src = tt.src[e];
  short* dst = tt.dst[e];
  const int tx = threadIdx.x & 31, ty = threadIdx.x >> 5;  // 32 x 8
  #pragma unroll
  for (int i = 0; i < 32; i += 8)
    tile[ty + i][tx] = f2bf(src[(size_t)(k0 + ty + i) * N + n0 + tx]);
  __syncthreads();
  #pragma unroll
  for (int i = 0; i < 32; i += 8)
    dst[(size_t)(n0 + ty + i) * K + k0 + tx] = tile[tx][ty + i];
}

// ---------- x + enc fp32 -> bf16, one launch (grid 8192) ----------
__global__ __launch_bounds__(256)
void convert_xe(const float* __restrict__ x, const float* __restrict__ enc,
                short* __restrict__ xc, short* __restrict__ encc)
{
  int b = blockIdx.x;
  const float* s; short* d;
  if (b < 4096) { s = x; d = xc; } else { s = enc; d = encc; b -= 4096; }
  const int i = (b * 256 + threadIdx.x) * 4;
  const floatx4 v = *(const floatx4*)(s + i);
  short4v o;
  #pragma unroll
  for (int j = 0; j < 4; j++) o[j] = f2bf(v[j]);
  *(short4v*)(d + i) = o;
}

// ---------- 19 x 1024-element fp32 param segments -> bf16 ----------
struct ParamMap { const float* s[19]; int off[19]; };
__global__ __launch_bounds__(256)
void convert_params(ParamMap pm, short* __restrict__ dst)
{
  const int b = blockIdx.x;
  for (int t = threadIdx.x; t < 1024; t += 256)
    dst[b * 1024 + t] = f2bf(pm.s[b][pm.off[b] + t]);
}

// 2D XCD partition (R10): physical block p runs on XCD p%8 (round-robin,
// verified R2). XCD x = (xr,xc) in 4x2 gets sub-grid bm in [xr*nbm/4 ..),
// bn in [xc*nbn/2 ..). Per-XCD unique panels: A/4 + B/2 (verified R11:
// ff1 FETCH 69.7 -> 41.0 MB). Needs nbm%4==0, nbn%2==0, grid%8==0.
__device__ __forceinline__ void xcd2d(int nbn, int& bm, int& bn) {
  const int x   = (int)blockIdx.x & 7;
  const int loc = (int)blockIdx.x >> 3;
  const int nbm = ((int)gridDim.x) / nbn;
  const int gm  = nbm >> 2;
  const int gn  = nbn >> 1;
  bm = (x >> 1) * gm + loc / gn;
  bn = (x & 1) * gn + loc % gn;
}

// ---------- GEMM (big tiles): C = A @ BT^T + bias (+resid)(+relu), bf16 ----------
// R4 structure: depth-1 prefetch, distinct LDS buffers, 2 barriers / 64-K.
// R7 chunk swizzle: conflict-free ds_read_b128 (counter 8.4M -> 0).
// Used for 128x128 (qkv1, ff1) and 64x128 (kv2). BK stays 32 here (m132:
// bigger K-tiles at 128x128 cost occupancy).
template<int RELU, int RESID, int BM, int BN>
__global__ __launch_bounds__(256)
void gemm_bt(const short* __restrict__ A, const short* __restrict__ BT,
             const short* __restrict__ bias, const short* __restrict__ resid,
             short* __restrict__ C, int M, int N, int K)
{
  constexpr int MT = BM / 32;            // a-frag repeats per wave
  constexpr int NT = BN / 32;            // b-frag repeats per wave
  __shared__ short8 As0[BM * 4];         // slot = 4*row + phys_chunk ; row 0..BM-1
  __shared__ short8 As1[BM * 4];
  __shared__ short8 Bs0[BN * 4];
  __shared__ short8 Bs1[BN * 4];
  const int tid  = threadIdx.x;
  const int w    = tid >> 6;
  const int lane = tid & 63;
  const int m16  = lane & 15;
  const int g    = lane >> 4;
  const int nbn  = N / BN;
  int bm, bn;
  xcd2d(nbn, bm, bn);                    // 2D XCD partition (R10)
  const int wm   = (w >> 1) * (BM / 2);
  const int wn   = (w & 1) * (BN / 2);

  // staging: lane -> (row + (lane>>2), phys chunk lane&3); pre-swizzled source:
  // phys chunk pc holds logical chunk pc ^ ((row>>1)&3).
  const int r0 = lane >> 2;
  const int c0 = lane & 3;
  const int csw = c0 ^ ((r0 >> 1) & 3);
  const short* pA = A  + (size_t)(bm * BM + w * (BM / 4) + r0) * K + csw * 8;
  const short* pB = BT + (size_t)(bn * BN + w * (BN / 4) + r0) * K + csw * 8;

  floatx4 acc[MT][NT];
  #pragma unroll
  for (int i = 0; i < MT; i++)
    #pragma unroll
    for (int j = 0; j < NT; j++)
      acc[i][j] = floatx4{0.f, 0.f, 0.f, 0.f};

  auto stage = [&](short8* AS, short8* BS, int k0) {
    async_cp16(pA + k0, AS + w * BM);
    if constexpr (BM == 128) async_cp16(pA + k0 + 16 * (size_t)K, AS + w * BM + 64);
    async_cp16(pB + k0, BS + w * BN);
    if constexpr (BN == 128) async_cp16(pB + k0 + 16 * (size_t)K, BS + w * BN + 64);
  };
  // fragment read: logical chunk g of row R lives at phys chunk g ^ ((R>>1)&3)
  const int gs = g ^ ((m16 >> 1) & 3);
  auto compute = [&](const short8* AS, const short8* BS) {
    short8 af[MT], bfr[NT];
    #pragma unroll
    for (int mt = 0; mt < MT; mt++)
      af[mt] = AS[(wm + mt * 16 + m16) * 4 + gs];
    #pragma unroll
    for (int nt = 0; nt < NT; nt++)
      bfr[nt] = BS[(wn + nt * 16 + m16) * 4 + gs];
    #pragma unroll
    for (int mt = 0; mt < MT; mt++)
      #pragma unroll
      for (int nt = 0; nt < NT; nt++)
        acc[mt][nt] = __builtin_amdgcn_mfma_f32_16x16x32_bf16(af[mt], bfr[nt], acc[mt][nt], 0, 0, 0);
  };

  stage(As0, Bs0, 0);
  __syncthreads();   // vmcnt(0) drain: buf0 ready

  for (int k0 = 0; k0 < K; k0 += 64) {
    stage(As1, Bs1, k0 + 32);     // issue next tile; overlaps compute below
    compute(As0, Bs0);
    __syncthreads();              // drain: buf1 ready; all waves done with buf0
    if (k0 + 64 < K)
      stage(As0, Bs0, k0 + 64);
    compute(As1, Bs1);
    __syncthreads();
  }

  // epilogue: C/D layout col=lane&15, row=(lane>>4)*4+reg
  #pragma unroll
  for (int mt = 0; mt < MT; mt++) {
    const int rbase = bm * BM + wm + mt * 16 + g * 4;
    #pragma unroll
    for (int nt = 0; nt < NT; nt++) {
      const int col = bn * BN + wn + nt * 16 + m16;
      const float bia = bf2f(bias[col]);
      #pragma unroll
      for (int r = 0; r < 4; r++) {
        const size_t idx = (size_t)(rbase + r) * N + col;
        float v = acc[mt][nt][r] + bia;
        if (RESID) v += bf2f(resid[idx]);
        if (RELU)  v = fmaxf(v, 0.f);
        C[idx] = f2bf(v);
      }
    }
  }
}

// ---------- GEMM 64x64, BK=64, depth-1 prefetch ----------
// R9: 2-barrier schedule with BK=64: per step 4 cp16 + 8 ds_read + 8 MFMA,
// half the barrier/drain count of BK=32 (verified: -23 us over the 4 N=1024
// GEMMs). LDS 32 KB, 4 blocks/CU.
// Swizzle (rows 128B = 8 chunks): stage source pre-swizzles logical chunk
// c0^r0; fragment read at phys ((4s+g) ^ (m16&7)). Rule #21: LDS linear,
// same involution both sides. Requires K%128==0.
template<int RELU, int RESID>
__global__ __launch_bounds__(256)
void gemm_bt64(const short* __restrict__ A, const short* __restrict__ BT,
               const short* __restrict__ bias, const short* __restrict__ resid,
               short* __restrict__ C, int M, int N, int K)
{
  __shared__ short8 As0[512], As1[512];   // [row(64)][phys chunk(8)] ; 8 KB each
  __shared__ short8 Bs0[512], Bs1[512];
  const int tid  = threadIdx.x;
  const int w    = tid >> 6;
  const int lane = tid & 63;
  const int m16  = lane & 15;
  const int g    = lane >> 4;
  const int nbn  = N >> 6;
  int bm, bn;
  xcd2d(nbn, bm, bn);                    // 2D XCD partition (R10)
  const int wm   = (w >> 1) << 5;
  const int wn   = (w & 1) << 5;

  // staging: wave w stages rows w*16..w*16+15 (two cp16 rounds of 8 rows each);
  // lane -> (row w*16 + (lane>>3) [+8], phys chunk lane&7); source pre-swizzle:
  // phys chunk pc holds logical chunk pc ^ (row&7); row&7 == lane>>3 both rounds.
  const int r0  = lane >> 3;              // 0..7
  const int c0  = lane & 7;
  const int csw = c0 ^ r0;
  const short* pA = A  + (size_t)(bm * 64 + w * 16 + r0) * K + csw * 8;
  const short* pB = BT + (size_t)(bn * 64 + w * 16 + r0) * K + csw * 8;

  floatx4 acc[2][2];
  #pragma unroll
  for (int i = 0; i < 2; i++)
    #pragma unroll
    for (int j = 0; j < 2; j++)
      acc[i][j] = floatx4{0.f, 0.f, 0.f, 0.f};

  auto stage = [&](short8* AS, short8* BS, int k0) {   // 4 vmem ops / wave
    async_cp16(pA + k0,                 AS + w * 128);
    async_cp16(pA + k0 + 8 * (size_t)K, AS + w * 128 + 64);
    async_cp16(pB + k0,                 BS + w * 128);
    async_cp16(pB + k0 + 8 * (size_t)K, BS + w * 128 + 64);
  };
  // fragment read: k-slice s (0,1) logical chunk 4s+g of row R lives at
  // phys (4s+g) ^ (R&7); R&7 == m16&7 (wm, mt*16 are multiples of 16).
  const int sw = m16 & 7;
  auto compute = [&](const short8* AS, const short8* BS) {
    #pragma unroll
    for (int s = 0; s < 2; s++) {
      const int pc = (4 * s + g) ^ sw;
      short8 af[2], bfr[2];
      #pragma unroll
      for (int mt = 0; mt < 2; mt++)
        af[mt] = AS[(wm + mt * 16 + m16) * 8 + pc];
      #pragma unroll
      for (int nt = 0; nt < 2; nt++)
        bfr[nt] = BS[(wn + nt * 16 + m16) * 8 + pc];
      #pragma unroll
      for (int mt = 0; mt < 2; mt++)
        #pragma unroll
        for (int nt = 0; nt < 2; nt++)
          acc[mt][nt] = __builtin_amdgcn_mfma_f32_16x16x32_bf16(af[mt], bfr[nt], acc[mt][nt], 0, 0, 0);
    }
  };

  stage(As0, Bs0, 0);
  __syncthreads();   // vmcnt(0) drain: buf0 ready

  for (int k0 = 0; k0 < K; k0 += 128) {
    stage(As1, Bs1, k0 + 64);     // issue next 64-K tile; overlaps compute below
    compute(As0, Bs0);
    __syncthreads();              // drain: buf1 ready; all waves done with buf0
    if (k0 + 128 < K)
      stage(As0, Bs0, k0 + 128);
    compute(As1, Bs1);
    __syncthreads();
  }

  // epilogue: C/D layout col=lane&15, row=(lane>>4)*4+reg
  #pragma unroll
  for (int mt = 0; mt < 2; mt++) {
    const int rbase = bm * 64 + wm + mt * 16 + g * 4;
    #pragma unroll
    for (int nt = 0; nt < 2; nt++) {
      const int col = bn * 64 + wn + nt * 16 + m16;
      const float bia = bf2f(bias[col]);
      #pragma unroll
      for (int r = 0; r < 4; r++) {
        const size_t idx = (size_t)(rbase + r) * N + col;
        float v = acc[mt][nt][r] + bia;
        if (RESID) v += bf2f(resid[idx]);
        if (RELU)  v = fmaxf(v, 0.f);
        C[idx] = f2bf(v);
      }
    }
  }
}

// ---------- flash attention: 128 q-rows/block (4 waves x 32), 64-key tiles, d=64, H=16 ----------
// R12: QBLK 64 -> 128. Each wave owns TWO 16-row q-groups (A: wrow+m16,
// B: +16), processed sequentially per key tile. Per tile: 16 LDS K/V frag
// reads + 1 barrier now feed 32 MFMA (was 16) -- 2x MFMA per barrier and per
// staged byte; K/V global traffic, ds_writes, and barrier instances halve
// (grid 1024 -> 512 = 2 blocks/CU). launch_bounds (256,2): occupancy is
// grid-limited at 2 blocks/CU, so no reason to cap VGPR at 128 (spill risk).
// R6 swapped-operand QK^T (q on lanes, in-register softmax) per group.
// R10 XCD swizzle: grid 512 = 8 x 64 -> XCD x gets 8 heads x 8 q-tiles of one
// batch; K/V working set 2 MB, L2-resident.
// LDS: Ks 16 KB + VT 16 KB + Ps[4][32*64] 16 KB = 48 KB.
template<int CAUSAL>
__global__ __launch_bounds__(256, 2)
void attention(const short* __restrict__ Qp, int ldq,
               const short* __restrict__ Kp, int ldk,
               const short* __restrict__ Vp, int ldv,
               short* __restrict__ Op, int ldo)
{
  const int S   = 1024;
  const int bid = (((int)blockIdx.x & 7) << 6) | ((int)blockIdx.x >> 3);  // XCD swizzle
  const int qt  = bid & 7;          // 8 q-tiles of 128
  const int h   = (bid >> 3) & 15;  // 16 heads
  const int b   = bid >> 7;         // 4 batches
  const int tid = threadIdx.x;
  const int w   = tid >> 6;
  const int lane = tid & 63;
  const int m16 = lane & 15;
  const int g   = lane >> 4;

  __shared__ __align__(16) short Ks[2][64 * 64];   // [buf][key][d], swizzled, 16 KiB
  __shared__ __align__(16) short VT[2][64 * 64];   // [buf][d][key], swizzled, 16 KiB
  __shared__ __align__(16) short Ps[4][32 * 64];   // per-wave P (32 q x 64 k), swizzled, 16 KiB

  const int rowQ = b * S + qt * 128;
  const int wrow = w * 32;

  // Q fragments straight from global (per-lane b128, loaded once); two groups
  const short* qsrcA = Qp + (size_t)(rowQ + wrow + m16) * ldq + h * 64 + 8 * g;
  const short* qsrcB = qsrcA + (size_t)16 * ldq;
  const short8 qfa0 = *(const short8*)qsrcA;
  const short8 qfa1 = *(const short8*)(qsrcA + 32);
  const short8 qfb0 = *(const short8*)qsrcB;
  const short8 qfb1 = *(const short8*)(qsrcB + 32);

  float mA = -1e38f, lA = 0.f;
  float mB = -1e38f, lB = 0.f;
  floatx4 oA[4], oB[4];
  #pragma unroll
  for (int dt = 0; dt < 4; dt++) { oA[dt] = floatx4{0.f,0.f,0.f,0.f}; oB[dt] = floatx4{0.f,0.f,0.f,0.f}; }

  // staging index precompute (unchanged from QBLK=64 version)
  const int kr  = tid >> 2, kc = (tid & 3) << 4;          // K: row, col (16-short chunk)
  const int vkp = (tid & 31) * 2, vcg = (tid >> 5) << 3;  // V: key pair, d-group

  const short* kbase = Kp + (size_t)(b * S + kr)  * ldk + h * 64 + kc;
  const short* vbase = Vp + (size_t)(b * S + vkp) * ldv + h * 64 + vcg;

  const int nkt = CAUSAL ? (2 * qt + 2) : (S / 64);
  const int qiA = qt * 128 + wrow + m16;   // group A q index (causal mask)
  const int qiB = qiA + 16;

  // ---- prologue: stage tile 0 into buf 0 ----
  short8 kst0 = *(const short8*)kbase;
  short8 kst1 = *(const short8*)(kbase + 8);
  short8 vst0 = *(const short8*)vbase;
  short8 vst1 = *(const short8*)(vbase + ldv);
  {
    char* kd = (char*)&Ks[0][0];
    *(short8*)(kd + swzb(kr, kc * 2))      = kst0;
    *(short8*)(kd + swzb(kr, kc * 2 + 16)) = kst1;
    char* vd = (char*)&VT[0][0];
    #pragma unroll
    for (int j = 0; j < 8; j++) {
      const uint32_t pk = (uint32_t)(uint16_t)vst0[j] | ((uint32_t)(uint16_t)vst1[j] << 16);
      *(uint32_t*)(vd + swzb(vcg + j, vkp * 2)) = pk;
    }
  }
  __syncthreads();

  for (int kt = 0; kt < nkt; kt++) {
    const int cur  = kt & 1;
    const int more = (kt + 1 < nkt);   // block-uniform

    // issue next-tile global loads NOW; latency hides under QK/softmax/PV
    if (more) {
      const size_t roff = (size_t)(kt + 1) * 64;
      kst0 = *(const short8*)(kbase + roff * ldk);
      kst1 = *(const short8*)(kbase + roff * ldk + 8);
      vst0 = *(const short8*)(vbase + roff * ldv);
      vst1 = *(const short8*)(vbase + roff * ldv + ldv);
    }

    const int kb = kt * 64;
    const int domask = CAUSAL && (kt >= 2 * qt);   // wave-uniform

    // scores^T for both q-groups; K fragments read once, used twice
    const char* ksrc = (const char*)&Ks[cur][0];
    floatx4 scA[4], scB[4];
    #pragma unroll
    for (int cg4 = 0; cg4 < 4; cg4++) {
      const short8 kfa = *(const short8*)(ksrc + swzb(cg4 * 16 + m16, 16 * g));
      const short8 kfb = *(const short8*)(ksrc + swzb(cg4 * 16 + m16, 64 + 16 * g));
      scA[cg4] = __builtin_amdgcn_mfma_f32_16x16x32_bf16(kfa, qfa0, floatx4{0.f,0.f,0.f,0.f}, 0, 0, 0);
      scA[cg4] = __builtin_amdgcn_mfma_f32_16x16x32_bf16(kfb, qfa1, scA[cg4], 0, 0, 0);
      scB[cg4] = __builtin_amdgcn_mfma_f32_16x16x32_bf16(kfa, qfb0, floatx4{0.f,0.f,0.f,0.f}, 0, 0, 0);
      scB[cg4] = __builtin_amdgcn_mfma_f32_16x16x32_bf16(kfb, qfb1, scB[cg4], 0, 0, 0);
    }

    char* pbase = (char*)&Ps[w][0];

    // ---- group A softmax (q = qiA) ----
    {
      float v4[4][4];
      #pragma unroll
      for (int cg = 0; cg < 4; cg++)
        #pragma unroll
        for (int r = 0; r < 4; r++) {
          float x = scA[cg][r] * 0.125f;
          if (domask) { const int key = kb + cg * 16 + g * 4 + r; if (key > qiA) x = -1e9f; }
          v4[cg][r] = x;
        }
      float mx = v4[0][0];
      #pragma unroll
      for (int cg = 0; cg < 4; cg++)
        #pragma unroll
        for (int r = 0; r < 4; r++) mx = fmaxf(mx, v4[cg][r]);
      mx = fmaxf(mx, __shfl_xor(mx, 16));
      mx = fmaxf(mx, __shfl_xor(mx, 32));
      const float mn = fmaxf(mA, mx);
      const float alpha = __expf(mA - mn);
      mA = mn;
      float rs = 0.f;
      #pragma unroll
      for (int cg = 0; cg < 4; cg++)
        #pragma unroll
        for (int r = 0; r < 4; r++) { v4[cg][r] = __expf(v4[cg][r] - mn); rs += v4[cg][r]; }
      rs += __shfl_xor(rs, 16);
      rs += __shfl_xor(rs, 32);
      lA = lA * alpha + rs;
      #pragma unroll
      for (int r = 0; r < 4; r++) {
        const float aR = __shfl(alpha, (g << 2) | r);
        #pragma unroll
        for (int dt = 0; dt < 4; dt++) oA[dt][r] *= aR;
      }
      #pragma unroll
      for (int cg = 0; cg < 4; cg++) {
        const uint32_t p0 = (uint32_t)(uint16_t)f2bf(v4[cg][0]) |
                            ((uint32_t)(uint16_t)f2bf(v4[cg][1]) << 16);
        const uint32_t p1 = (uint32_t)(uint16_t)f2bf(v4[cg][2]) |
                            ((uint32_t)(uint16_t)f2bf(v4[cg][3]) << 16);
        *(uint32_t*)(pbase + swzb(m16, (8 * cg + 2 * g) * 4))     = p0;
        *(uint32_t*)(pbase + swzb(m16, (8 * cg + 2 * g + 1) * 4)) = p1;
      }
    }

    // ---- group B softmax (q = qiB, P rows 16..31) ----
    {
      float v4[4][4];
      #pragma unroll
      for (int cg = 0; cg < 4; cg++)
        #pragma unroll
        for (int r = 0; r < 4; r++) {
          float x = scB[cg][r] * 0.125f;
          if (domask) { const int key = kb + cg * 16 + g * 4 + r; if (key > qiB) x = -1e9f; }
          v4[cg][r] = x;
        }
      float mx = v4[0][0];
      #pragma unroll
      for (int cg = 0; cg < 4; cg++)
        #pragma unroll
        for (int r = 0; r < 4; r++) mx = fmaxf(mx, v4[cg][r]);
      mx = fmaxf(mx, __shfl_xor(mx, 16));
      mx = fmaxf(mx, __shfl_xor(mx, 32));
      const float mn = fmaxf(mB, mx);
      const float alpha = __expf(mB - mn);
      mB = mn;
      float rs = 0.f;
      #pragma unroll
      for (int cg = 0; cg < 4; cg++)
        #pragma unroll
        for (int r = 0; r < 4; r++) { v4[cg][r] = __expf(v4[cg][r] - mn); rs += v4[cg][r]; }
      rs += __shfl_xor(rs, 16);
      rs += __shfl_xor(rs, 32);
      lB = lB * alpha + rs;
      #pragma unroll
      for (int r = 0; r < 4; r++) {
        const float aR = __shfl(alpha, (g << 2) | r);
        #pragma unroll
        for (int dt = 0; dt < 4; dt++) oB[dt][r] *= aR;
      }
      #pragma unroll
      for (int cg = 0; cg < 4; cg++) {
        const uint32_t p0 = (uint32_t)(uint16_t)f2bf(v4[cg][0]) |
                            ((uint32_t)(uint16_t)f2bf(v4[cg][1]) << 16);
        const uint32_t p1 = (uint32_t)(uint16_t)f2bf(v4[cg][2]) |
                            ((uint32_t)(uint16_t)f2bf(v4[cg][3]) << 16);
        *(uint32_t*)(pbase + swzb(16 + m16, (8 * cg + 2 * g) * 4))     = p0;
        *(uint32_t*)(pbase + swzb(16 + m16, (8 * cg + 2 * g + 1) * 4)) = p1;
      }
    }

    // P write -> P read is same-wave only (Ps is per-wave): lgkm drain, no barrier.
    asm volatile("s_waitcnt lgkmcnt(0)" ::: "memory");
    __builtin_amdgcn_sched_barrier(0);

    // PV for both groups: V fragments read once, used twice
    const short8 pfa0 = *(const short8*)(pbase + swzb(m16, 16 * g));
    const short8 pfa1 = *(const short8*)(pbase + swzb(m16, 64 + 16 * g));
    const short8 pfb0 = *(const short8*)(pbase + swzb(16 + m16, 16 * g));
    const short8 pfb1 = *(const short8*)(pbase + swzb(16 + m16, 64 + 16 * g));
    const char* vsrc = (const char*)&VT[cur][0];
    #pragma unroll
    for (int dt = 0; dt < 4; dt++) {
      const short8 vfa = *(const short8*)(vsrc + swzb(dt * 16 + m16, 16 * g));
      const short8 vfb = *(const short8*)(vsrc + swzb(dt * 16 + m16, 64 + 16 * g));
      oA[dt] = __builtin_amdgcn_mfma_f32_16x16x32_bf16(pfa0, vfa, oA[dt], 0, 0, 0);
      oA[dt] = __builtin_amdgcn_mfma_f32_16x16x32_bf16(pfa1, vfb, oA[dt], 0, 0, 0);
      oB[dt] = __builtin_amdgcn_mfma_f32_16x16x32_bf16(pfb0, vfa, oB[dt], 0, 0, 0);
      oB[dt] = __builtin_amdgcn_mfma_f32_16x16x32_bf16(pfb1, vfb, oB[dt], 0, 0, 0);
    }

    // write prefetched tile into the other buffer; single barrier per tile.
    if (more) {
      char* kd = (char*)&Ks[cur ^ 1][0];
      *(short8*)(kd + swzb(kr, kc * 2))      = kst0;
      *(short8*)(kd + swzb(kr, kc * 2 + 16)) = kst1;
      char* vd = (char*)&VT[cur ^ 1][0];
      #pragma unroll
      for (int j = 0; j < 8; j++) {
        const uint32_t pk = (uint32_t)(uint16_t)vst0[j] | ((uint32_t)(uint16_t)vst1[j] << 16);
        *(uint32_t*)(vd + swzb(vcg + j, vkp * 2)) = pk;
      }
      __syncthreads();
    }
  }

  // epilogue: O row = q = g*4+r within each group; l lives in lane g*4+r
  float lRA[4], lRB[4];
  #pragma unroll
  for (int r = 0; r < 4; r++) {
    lRA[r] = __shfl(lA, (g << 2) | r);
    lRB[r] = __shfl(lB, (g << 2) | r);
  }
  #pragma unroll
  for (int dt = 0; dt < 4; dt++)
    #pragma unroll
    for (int r = 0; r < 4; r++) {
      const size_t orowA = (size_t)(rowQ + wrow + g * 4 + r);
      Op[orowA * ldo + h * 64 + dt * 16 + m16] = f2bf(oA[dt][r] / lRA[r]);
      const size_t orowB = orowA + 16;
      Op[orowB * ldo + h * 64 + dt * 16 + m16] = f2bf(oB[dt][r] / lRB[r]);
    }
}

// ---------- LayerNorm over D=1024; FINAL=1 stores fp32 ----------
template<int FINAL>
__global__ __launch_bounds__(256)
void layernorm_bf16(const short* __restrict__ x, const short* __restrict__ gamma,
                    const short* __restrict__ beta, void* __restrict__ out)
{
  const int D = 1024;
  const int row = blockIdx.x, tid = threadIdx.x;
  const short* xr = x + (size_t)row * D;
  short4v xv = *(const short4v*)(xr + tid * 4);
  float v[4], s = 0.f, ss = 0.f;
  #pragma unroll
  for (int j = 0; j < 4; j++) { v[j] = bf2f(xv[j]); s += v[j]; ss += v[j] * v[j]; }
  #pragma unroll
  for (int off = 32; off; off >>= 1) { s += __shfl_xor(s, off); ss += __shfl_xor(ss, off); }
  __shared__ float red[8];
  const int w = tid >> 6, lane = tid & 63;
  if (lane == 0) { red[w] = s; red[4 + w] = ss; }
  __syncthreads();
  s  = red[0] + red[1] + red[2] + red[3];
  ss = red[4] + red[5] + red[6] + red[7];
  const float mean = s * (1.f / D);
  const float var  = ss * (1.f / D) - mean * mean;
  const float inv  = rsqrtf(var + 1e-3f);
  float o[4];
  #pragma unroll
  for (int j = 0; j < 4; j++)
    o[j] = (v[j] - mean) * inv * bf2f(gamma[tid * 4 + j]) + bf2f(beta[tid * 4 + j]);
  if (FINAL) {
    floatx4 ov;
    #pragma unroll
    for (int j = 0; j < 4; j++) ov[j] = o[j];
    *(floatx4*)((float*)out + (size_t)row * D + tid * 4) = ov;
  } else {
    short4v ov;
    #pragma unroll
    for (int j = 0; j < 4; j++) ov[j] = f2bf(o[j]);
    *(short4v*)((short*)out + (size_t)row * D + tid * 4) = ov;
  }
}

// ---------- host ----------
extern "C" void kernel_launch(void* const* d_in, const int* in_sizes, int n_in,
                              void* d_out, int out_size, void* d_ws, size_t ws_size,
                              hipStream_t stream) {
  (void)in_sizes; (void)n_in; (void)out_size; (void)ws_size;
  const int M = 4096;
  const size_t MM = 1024 * 1024;

  short* ws = (short*)d_ws;
  short* wt_qkv1 = ws;                   // [3072][1024]
  short* wt_o1   = wt_qkv1 + 3 * MM;
  short* wt_q2   = wt_o1 + MM;
  short* wt_kv2  = wt_q2 + MM;           // [2048][1024]
  short* wt_o2   = wt_kv2 + 2 * MM;
  short* wt_ff1  = wt_o2 + MM;           // [4096][1024]
  short* wt_ff2  = wt_ff1 + 4 * MM;      // [1024][4096]
  short* P       = ws + 16 * MM;         // 19456 param shorts
  short* encc    = ws + 16 * MM + 32768; // 4M enc bf16
  short* act0    = encc + 4 * MM;        // 16M: qkv1 | kv2+q2 | ffn-hidden
  short* attn    = act0 + 16 * MM;       // 4M
  short* t1      = attn + 4 * MM;        // 4M
  short* t2      = t1 + 4 * MM;          // 4M; xc aliases t2 (dead before t2 written)
  short* xc      = t2;

  short* bqkv1 = P,        *bo1  = P + 3072, *bkv2 = P + 4096, *bq2 = P + 6144;
  short* bo2   = P + 7168, *bff1 = P + 8192, *bff2 = P + 12288;
  short* g1 = P + 13312, *be1 = P + 14336, *g2 = P + 15360, *be2 = P + 16384;
  short* g3 = P + 17408, *be3 = P + 18432;

  // 1) params fp32 -> bf16 (19 x 1024 segments, 1 launch)
  ParamMap pm;
  const int srcidx[19] = {6, 7, 8, 9, 15, 16, 14, 17, 19, 19, 19, 19, 21, 22, 23, 24, 25, 26, 27};
  const int offs[19]   = {0, 0, 0, 0, 0,  0,  0,  0,  0, 1024, 2048, 3072, 0, 0, 0, 0, 0, 0, 0};
  for (int i = 0; i < 19; i++) { pm.s[i] = (const float*)d_in[srcidx[i]]; pm.off[i] = offs[i]; }
  convert_params<<<19, 256, 0, stream>>>(pm, P);

  // 2) x, enc fp32 -> bf16 (1 launch)
  convert_xe<<<8192, 256, 0, stream>>>((const float*)d_in[0], (const float*)d_in[1], xc, encc);

  // 3) all 10 weight transposes (1 launch, 16384 tiles)
  TransTable tt;
  const int widx[10] = {2, 3, 4, 5, 10, 11, 12, 13, 18, 20};
  short* wdst[10] = {wt_qkv1, wt_qkv1 + MM, wt_qkv1 + 2 * MM, wt_o1, wt_q2,
                     wt_kv2, wt_kv2 + MM, wt_o2, wt_ff1, wt_ff2};
  const int wK[10] = {1024, 1024, 1024, 1024, 1024, 1024, 1024, 1024, 1024, 4096};
  const int wN[10] = {1024, 1024, 1024, 1024, 1024, 1024, 1024, 1024, 4096, 1024};
  int base = 0;
  for (int i = 0; i < 10; i++) {
    tt.src[i] = (const float*)d_in[widx[i]];
    tt.dst[i] = wdst[i];
    tt.K[i] = wK[i]; tt.N[i] = wN[i]; tt.base[i] = base;
    base += (wN[i] / 32) * (wK[i] / 32);
  }
  transpose_all<<<base, 256, 0, stream>>>(tt);   // base = 16384

  // 4) self-attention block
  short* qkv1 = act0;  // [4096][3072]
  gemm_bt<0, 0, 128, 128><<<dim3((M / 128) * (3072 / 128)), 256, 0, stream>>>(
      xc, wt_qkv1, bqkv1, nullptr, qkv1, M, 3072, 1024);
  attention<1><<<dim3(512), 256, 0, stream>>>(
      qkv1, 3072, qkv1 + 1024, 3072, qkv1 + 2048, 3072, attn, 1024);
  gemm_bt64<0, 1><<<dim3((M / 64) * (1024 / 64)), 256, 0, stream>>>(
      attn, wt_o1, bo1, xc, t1, M, 1024, 1024);
  layernorm_bf16<0><<<dim3(4096), 256, 0, stream>>>(t1, g1, be1, t1);  // o1 in place

  // 5) cross-attention block
  short* kv2 = act0;            // [4096][2048]
  short* q2  = act0 + 8 * MM;   // [4096][1024]
  gemm_bt<0, 0, 64, 128><<<dim3((M / 64) * (2048 / 128)), 256, 0, stream>>>(
      encc, wt_kv2, bkv2, nullptr, kv2, M, 2048, 1024);
  gemm_bt64<0, 0><<<dim3((M / 64) * (1024 / 64)), 256, 0, stream>>>(
      t1, wt_q2, bq2, nullptr, q2, M, 1024, 1024);
  attention<0><<<dim3(512), 256, 0, stream>>>(
      q2, 1024, kv2, 2048, kv2 + 1024, 2048, attn, 1024);
  gemm_bt64<0, 1><<<dim3((M / 64) * (1024 / 64)), 256, 0, stream>>>(
      attn, wt_o2, bo2, t1, t2, M, 1024, 1024);
  layernorm_bf16<0><<<dim3(4096), 256, 0, stream>>>(t2, g2, be2, t2);  // o2 in place

  // 6) FFN block
  short* hidden = act0;  // [4096][4096]
  gemm_bt<1, 0, 128, 128><<<dim3((M / 128) * (4096 / 128)), 256, 0, stream>>>(
      t2, wt_ff1, bff1, nullptr, hidden, M, 4096, 1024);
  gemm_bt64<0, 1><<<dim3((M / 64) * (1024 / 64)), 256, 0, stream>>>(
      hidden, wt_ff2, bff2, t2, attn, M, 1024, 4096);
  layernorm_bf16<1><<<dim3(4096), 256, 0, stream>>>(attn, g3, be3, d_out);
}

// Round 13
// 481.785 us; speedup vs baseline: 1.0286x; 1.0286x over previous
//
#include <hip/hip_runtime.h>
#include <stdint.h>
#include <stddef.h>

// ---------- types ----------
typedef __attribute__((ext_vector_type(4))) float  floatx4;
typedef __attribute__((ext_vector_type(8))) short  short8;   // 8 bf16 (MFMA A/B frag)
typedef __attribute__((ext_vector_type(4))) short  short4v;

__device__ __forceinline__ float bf2f(short s) {
  union { uint32_t u; float f; } v;
  v.u = ((uint32_t)(uint16_t)s) << 16;
  return v.f;
}
__device__ __forceinline__ short f2bf(float f) {
  union { float f; uint32_t u; } v; v.f = f;
  uint32_t r = v.u + 0x7fffu + ((v.u >> 16) & 1u);   // RNE
  return (short)(r >> 16);
}

__device__ __forceinline__ void async_cp16(const void* g, void* l) {
  __builtin_amdgcn_global_load_lds(
      (__attribute__((address_space(1))) void*)g,
      (__attribute__((address_space(3))) void*)l, 16, 0, 0);
}

// XOR-swizzle byte offset inside a [row][128B] LDS tile: spreads the 128B-row
// bank collision (guide G4: byte ^= (row&7)<<4), bijective per row, keeps 16B align.
__device__ __forceinline__ int swzb(int row, int bcol) {
  return ((row << 7) + bcol) ^ ((row & 7) << 4);
}

// ---------- merged preprocessing: params->bf16 | x/enc->bf16 | 10 weight transposes ----------
// R13: one launch instead of three. Blocks [0,19) = param segments; [19,8211) =
// x/enc convert; [8211,24595) = fp32(KxN) -> bf16(NxK) transposes. The three
// phases are independent; merging removes 2 launch gaps and lets the grids'
// tails overlap. Per-block uniform branch; early return before the transpose
// path's __syncthreads is block-local and legal.
struct PreArgs {
  const float* ps[19]; int poff[19];
  short* pdst;
  const float* x; const float* enc; short* xc; short* encc;
  const float* tsrc[10];
  short*       tdst[10];
  int tK[10], tN[10], tbase[10];
};
__global__ __launch_bounds__(256)
void preprocess(PreArgs pa)
{
  __shared__ short tile[32][33];
  int b = blockIdx.x;
  if (b < 19) {
    for (int t = threadIdx.x; t < 1024; t += 256)
      pa.pdst[b * 1024 + t] = f2bf(pa.ps[b][pa.poff[b] + t]);
    return;
  }
  b -= 19;
  if (b < 8192) {
    const float* s; short* d;
    if (b < 4096) { s = pa.x; d = pa.xc; } else { s = pa.enc; d = pa.encc; b -= 4096; }
    const int i = (b * 256 + threadIdx.x) * 4;
    const floatx4 v = *(const floatx4*)(s + i);
    short4v o;
    #pragma unroll
    for (int j = 0; j < 4; j++) o[j] = f2bf(v[j]);
    *(short4v*)(d + i) = o;
    return;
  }
  b -= 8192;
  int e = 0;
  #pragma unroll
  for (int i = 1; i < 10; i++) if (b >= pa.tbase[i]) e = i;
  const int t = b - pa.tbase[e];
  const int N = pa.tN[e], K = pa.tK[e];
  const int ncols = N >> 5;
  const int n0 = (t % ncols) << 5, k0 = (t / ncols) << 5;
  const float* src = pa.tsrc[e];
  short* dst = pa.tdst[e];
  const int tx = threadIdx.x & 31, ty = threadIdx.x >> 5;  // 32 x 8
  #pragma unroll
  for (int i = 0; i < 32; i += 8)
    tile[ty + i][tx] = f2bf(src[(size_t)(k0 + ty + i) * N + n0 + tx]);
  __syncthreads();
  #pragma unroll
  for (int i = 0; i < 32; i += 8)
    dst[(size_t)(n0 + ty + i) * K + k0 + tx] = tile[tx][ty + i];
}

// 2D XCD partition (R10): physical block p runs on XCD p%8 (round-robin,
// verified R2). XCD x = (xr,xc) in 4x2 gets sub-grid bm in [xr*nbm/4 ..),
// bn in [xc*nbn/2 ..). Per-XCD unique panels: A/4 + B/2 (verified R11:
// ff1 FETCH 69.7 -> 41.0 MB). Needs nbm%4==0, nbn%2==0, grid%8==0.
__device__ __forceinline__ void xcd2d(int nbn, int& bm, int& bn) {
  const int x   = (int)blockIdx.x & 7;
  const int loc = (int)blockIdx.x >> 3;
  const int nbm = ((int)gridDim.x) / nbn;
  const int gm  = nbm >> 2;
  const int gn  = nbn >> 1;
  bm = (x >> 1) * gm + loc / gn;
  bn = (x & 1) * gn + loc % gn;
}

// ---------- GEMM (big tiles): C = A @ BT^T + bias (+resid)(+relu), bf16 ----------
// R4 structure: depth-1 prefetch, distinct LDS buffers, 2 barriers / 64-K.
// R7 chunk swizzle: conflict-free ds_read_b128 (counter 8.4M -> 0).
// Used for 128x128 (qkv1, ff1) and 64x128 (kv2). BK stays 32 here (m132:
// bigger K-tiles at 128x128 cost occupancy).
template<int RELU, int RESID, int BM, int BN>
__global__ __launch_bounds__(256)
void gemm_bt(const short* __restrict__ A, const short* __restrict__ BT,
             const short* __restrict__ bias, const short* __restrict__ resid,
             short* __restrict__ C, int M, int N, int K)
{
  constexpr int MT = BM / 32;            // a-frag repeats per wave
  constexpr int NT = BN / 32;            // b-frag repeats per wave
  __shared__ short8 As0[BM * 4];         // slot = 4*row + phys_chunk ; row 0..BM-1
  __shared__ short8 As1[BM * 4];
  __shared__ short8 Bs0[BN * 4];
  __shared__ short8 Bs1[BN * 4];
  const int tid  = threadIdx.x;
  const int w    = tid >> 6;
  const int lane = tid & 63;
  const int m16  = lane & 15;
  const int g    = lane >> 4;
  const int nbn  = N / BN;
  int bm, bn;
  xcd2d(nbn, bm, bn);                    // 2D XCD partition (R10)
  const int wm   = (w >> 1) * (BM / 2);
  const int wn   = (w & 1) * (BN / 2);

  // staging: lane -> (row + (lane>>2), phys chunk lane&3); pre-swizzled source:
  // phys chunk pc holds logical chunk pc ^ ((row>>1)&3).
  const int r0 = lane >> 2;
  const int c0 = lane & 3;
  const int csw = c0 ^ ((r0 >> 1) & 3);
  const short* pA = A  + (size_t)(bm * BM + w * (BM / 4) + r0) * K + csw * 8;
  const short* pB = BT + (size_t)(bn * BN + w * (BN / 4) + r0) * K + csw * 8;

  floatx4 acc[MT][NT];
  #pragma unroll
  for (int i = 0; i < MT; i++)
    #pragma unroll
    for (int j = 0; j < NT; j++)
      acc[i][j] = floatx4{0.f, 0.f, 0.f, 0.f};

  auto stage = [&](short8* AS, short8* BS, int k0) {
    async_cp16(pA + k0, AS + w * BM);
    if constexpr (BM == 128) async_cp16(pA + k0 + 16 * (size_t)K, AS + w * BM + 64);
    async_cp16(pB + k0, BS + w * BN);
    if constexpr (BN == 128) async_cp16(pB + k0 + 16 * (size_t)K, BS + w * BN + 64);
  };
  // fragment read: logical chunk g of row R lives at phys chunk g ^ ((R>>1)&3)
  const int gs = g ^ ((m16 >> 1) & 3);
  auto compute = [&](const short8* AS, const short8* BS) {
    short8 af[MT], bfr[NT];
    #pragma unroll
    for (int mt = 0; mt < MT; mt++)
      af[mt] = AS[(wm + mt * 16 + m16) * 4 + gs];
    #pragma unroll
    for (int nt = 0; nt < NT; nt++)
      bfr[nt] = BS[(wn + nt * 16 + m16) * 4 + gs];
    #pragma unroll
    for (int mt = 0; mt < MT; mt++)
      #pragma unroll
      for (int nt = 0; nt < NT; nt++)
        acc[mt][nt] = __builtin_amdgcn_mfma_f32_16x16x32_bf16(af[mt], bfr[nt], acc[mt][nt], 0, 0, 0);
  };

  stage(As0, Bs0, 0);
  __syncthreads();   // vmcnt(0) drain: buf0 ready

  for (int k0 = 0; k0 < K; k0 += 64) {
    stage(As1, Bs1, k0 + 32);     // issue next tile; overlaps compute below
    compute(As0, Bs0);
    __syncthreads();              // drain: buf1 ready; all waves done with buf0
    if (k0 + 64 < K)
      stage(As0, Bs0, k0 + 64);
    compute(As1, Bs1);
    __syncthreads();
  }

  // epilogue: C/D layout col=lane&15, row=(lane>>4)*4+reg
  #pragma unroll
  for (int mt = 0; mt < MT; mt++) {
    const int rbase = bm * BM + wm + mt * 16 + g * 4;
    #pragma unroll
    for (int nt = 0; nt < NT; nt++) {
      const int col = bn * BN + wn + nt * 16 + m16;
      const float bia = bf2f(bias[col]);
      #pragma unroll
      for (int r = 0; r < 4; r++) {
        const size_t idx = (size_t)(rbase + r) * N + col;
        float v = acc[mt][nt][r] + bia;
        if (RESID) v += bf2f(resid[idx]);
        if (RELU)  v = fmaxf(v, 0.f);
        C[idx] = f2bf(v);
      }
    }
  }
}

// ---------- GEMM 64x64, BK=64, depth-1 prefetch ----------
// R9: 2-barrier schedule with BK=64: per step 4 cp16 + 8 ds_read + 8 MFMA,
// half the barrier/drain count of BK=32 (verified: -23 us over the 4 N=1024
// GEMMs). LDS 32 KB, 4 blocks/CU.
// Swizzle (rows 128B = 8 chunks): stage source pre-swizzles logical chunk
// c0^r0; fragment read at phys ((4s+g) ^ (m16&7)). Rule #21: LDS linear,
// same involution both sides. Requires K%128==0.
template<int RELU, int RESID>
__global__ __launch_bounds__(256)
void gemm_bt64(const short* __restrict__ A, const short* __restrict__ BT,
               const short* __restrict__ bias, const short* __restrict__ resid,
               short* __restrict__ C, int M, int N, int K)
{
  __shared__ short8 As0[512], As1[512];   // [row(64)][phys chunk(8)] ; 8 KB each
  __shared__ short8 Bs0[512], Bs1[512];
  const int tid  = threadIdx.x;
  const int w    = tid >> 6;
  const int lane = tid & 63;
  const int m16  = lane & 15;
  const int g    = lane >> 4;
  const int nbn  = N >> 6;
  int bm, bn;
  xcd2d(nbn, bm, bn);                    // 2D XCD partition (R10)
  const int wm   = (w >> 1) << 5;
  const int wn   = (w & 1) << 5;

  // staging: wave w stages rows w*16..w*16+15 (two cp16 rounds of 8 rows each);
  // lane -> (row w*16 + (lane>>3) [+8], phys chunk lane&7); source pre-swizzle:
  // phys chunk pc holds logical chunk pc ^ (row&7); row&7 == lane>>3 both rounds.
  const int r0  = lane >> 3;              // 0..7
  const int c0  = lane & 7;
  const int csw = c0 ^ r0;
  const short* pA = A  + (size_t)(bm * 64 + w * 16 + r0) * K + csw * 8;
  const short* pB = BT + (size_t)(bn * 64 + w * 16 + r0) * K + csw * 8;

  floatx4 acc[2][2];
  #pragma unroll
  for (int i = 0; i < 2; i++)
    #pragma unroll
    for (int j = 0; j < 2; j++)
      acc[i][j] = floatx4{0.f, 0.f, 0.f, 0.f};

  auto stage = [&](short8* AS, short8* BS, int k0) {   // 4 vmem ops / wave
    async_cp16(pA + k0,                 AS + w * 128);
    async_cp16(pA + k0 + 8 * (size_t)K, AS + w * 128 + 64);
    async_cp16(pB + k0,                 BS + w * 128);
    async_cp16(pB + k0 + 8 * (size_t)K, BS + w * 128 + 64);
  };
  // fragment read: k-slice s (0,1) logical chunk 4s+g of row R lives at
  // phys (4s+g) ^ (R&7); R&7 == m16&7 (wm, mt*16 are multiples of 16).
  const int sw = m16 & 7;
  auto compute = [&](const short8* AS, const short8* BS) {
    #pragma unroll
    for (int s = 0; s < 2; s++) {
      const int pc = (4 * s + g) ^ sw;
      short8 af[2], bfr[2];
      #pragma unroll
      for (int mt = 0; mt < 2; mt++)
        af[mt] = AS[(wm + mt * 16 + m16) * 8 + pc];
      #pragma unroll
      for (int nt = 0; nt < 2; nt++)
        bfr[nt] = BS[(wn + nt * 16 + m16) * 8 + pc];
      #pragma unroll
      for (int mt = 0; mt < 2; mt++)
        #pragma unroll
        for (int nt = 0; nt < 2; nt++)
          acc[mt][nt] = __builtin_amdgcn_mfma_f32_16x16x32_bf16(af[mt], bfr[nt], acc[mt][nt], 0, 0, 0);
    }
  };

  stage(As0, Bs0, 0);
  __syncthreads();   // vmcnt(0) drain: buf0 ready

  for (int k0 = 0; k0 < K; k0 += 128) {
    stage(As1, Bs1, k0 + 64);     // issue next 64-K tile; overlaps compute below
    compute(As0, Bs0);
    __syncthreads();              // drain: buf1 ready; all waves done with buf0
    if (k0 + 128 < K)
      stage(As0, Bs0, k0 + 128);
    compute(As1, Bs1);
    __syncthreads();
  }

  // epilogue: C/D layout col=lane&15, row=(lane>>4)*4+reg
  #pragma unroll
  for (int mt = 0; mt < 2; mt++) {
    const int rbase = bm * 64 + wm + mt * 16 + g * 4;
    #pragma unroll
    for (int nt = 0; nt < 2; nt++) {
      const int col = bn * 64 + wn + nt * 16 + m16;
      const float bia = bf2f(bias[col]);
      #pragma unroll
      for (int r = 0; r < 4; r++) {
        const size_t idx = (size_t)(rbase + r) * N + col;
        float v = acc[mt][nt][r] + bia;
        if (RESID) v += bf2f(resid[idx]);
        if (RELU)  v = fmaxf(v, 0.f);
        C[idx] = f2bf(v);
      }
    }
  }
}

// ---------- flash attention v2: 64 q-rows/block (4 waves x 16), 64-key tiles, d=64, H=16 ----------
// R13: reverted to the verified R11 QBLK=64 structure (R12's QBLK=128 was
// neutral-to-negative: staging was already hidden at 4 blocks/CU; grid 512 =
// 2 blocks/CU lost latency coverage).
// R6 swapped-operand QK^T puts q on lanes; softmax row-reduce = 16 in-register
// + 2 shfl_xor; m/l per-lane scalars. R10 XCD swizzle: grid 1024 = 8 x 128 ->
// XCD x gets 8 heads x 16 q-tiles of one batch; K/V working set 2 MB, L2-resident.
// K/V double-buffered in LDS (XOR-swizzled), next tile prefetched into registers
// (ds_write after PV). ONE __syncthreads per key tile. LDS 40960 B.
template<int CAUSAL>
__global__ __launch_bounds__(256, 4)
void attention(const short* __restrict__ Qp, int ldq,
               const short* __restrict__ Kp, int ldk,
               const short* __restrict__ Vp, int ldv,
               short* __restrict__ Op, int ldo)
{
  const int S   = 1024;
  const int bid = (((int)blockIdx.x & 7) << 7) | ((int)blockIdx.x >> 3);  // XCD swizzle
  const int qt  = bid & 15;         // 16 q-tiles
  const int h   = (bid >> 4) & 15;  // 16 heads
  const int b   = bid >> 8;
  const int tid = threadIdx.x;
  const int w   = tid >> 6;
  const int lane = tid & 63;
  const int m16 = lane & 15;
  const int g   = lane >> 4;

  __shared__ __align__(16) short Ks[2][64 * 64];   // [buf][key][d], swizzled, 16 KiB
  __shared__ __align__(16) short VT[2][64 * 64];   // [buf][d][key], swizzled, 16 KiB
  __shared__ __align__(16) short Ps[4][16 * 64];   // per-wave P (16 q x 64 k), swizzled, 8 KiB

  const int rowQ = b * S + qt * 64;
  const int wrow = w * 16;

  // Q fragments straight from global (per-lane b128, loaded once)
  const short* qsrc = Qp + (size_t)(rowQ + wrow + m16) * ldq + h * 64 + 8 * g;
  const short8 qf0 = *(const short8*)qsrc;
  const short8 qf1 = *(const short8*)(qsrc + 32);

  // per-lane online-softmax state for q = wrow + m16 (replicated across g-groups)
  float mrow = -1e38f;
  float lrow = 0.f;
  floatx4 oacc[4];
  #pragma unroll
  for (int dt = 0; dt < 4; dt++) oacc[dt] = floatx4{0.f, 0.f, 0.f, 0.f};

  // staging index precompute
  const int kr  = tid >> 2, kc = (tid & 3) << 4;          // K: row, col (16-short chunk)
  const int vkp = (tid & 31) * 2, vcg = (tid >> 5) << 3;  // V: key pair, d-group

  const short* kbase = Kp + (size_t)(b * S + kr)  * ldk + h * 64 + kc;
  const short* vbase = Vp + (size_t)(b * S + vkp) * ldv + h * 64 + vcg;

  const int nkt = CAUSAL ? (qt + 1) : (S / 64);
  const int qi  = qt * 64 + wrow + m16;   // this lane's q index (for causal mask)

  // ---- prologue: stage tile 0 into buf 0 ----
  short8 kst0 = *(const short8*)kbase;
  short8 kst1 = *(const short8*)(kbase + 8);
  short8 vst0 = *(const short8*)vbase;
  short8 vst1 = *(const short8*)(vbase + ldv);
  {
    char* kd = (char*)&Ks[0][0];
    *(short8*)(kd + swzb(kr, kc * 2))      = kst0;
    *(short8*)(kd + swzb(kr, kc * 2 + 16)) = kst1;
    char* vd = (char*)&VT[0][0];
    #pragma unroll
    for (int j = 0; j < 8; j++) {
      const uint32_t pk = (uint32_t)(uint16_t)vst0[j] | ((uint32_t)(uint16_t)vst1[j] << 16);
      *(uint32_t*)(vd + swzb(vcg + j, vkp * 2)) = pk;
    }
  }
  __syncthreads();

  for (int kt = 0; kt < nkt; kt++) {
    const int cur  = kt & 1;
    const int more = (kt + 1 < nkt);   // block-uniform

    // issue next-tile global loads NOW; latency hides under QK/softmax/PV
    if (more) {
      const size_t roff = (size_t)(kt + 1) * 64;
      kst0 = *(const short8*)(kbase + roff * ldk);
      kst1 = *(const short8*)(kbase + roff * ldk + 8);
      vst0 = *(const short8*)(vbase + roff * ldv);
      vst1 = *(const short8*)(vbase + roff * ldv + ldv);
    }

    const int kb = kt * 64;

    // scores^T: A = K rows (keys cg*16+m16... -> C row=key), B = Q (C col=q=m16)
    const char* ksrc = (const char*)&Ks[cur][0];
    floatx4 sc[4];
    #pragma unroll
    for (int cg4 = 0; cg4 < 4; cg4++) {
      const short8 kfa = *(const short8*)(ksrc + swzb(cg4 * 16 + m16, 16 * g));
      const short8 kfb = *(const short8*)(ksrc + swzb(cg4 * 16 + m16, 64 + 16 * g));
      sc[cg4] = __builtin_amdgcn_mfma_f32_16x16x32_bf16(kfa, qf0, floatx4{0.f,0.f,0.f,0.f}, 0, 0, 0);
      sc[cg4] = __builtin_amdgcn_mfma_f32_16x16x32_bf16(kfb, qf1, sc[cg4], 0, 0, 0);
    }

    // lane holds S[q=m16][key = kb + cg*16 + g*4 + r] for cg,r in [0,4)
    float v4[4][4];
    #pragma unroll
    for (int cg = 0; cg < 4; cg++)
      #pragma unroll
      for (int r = 0; r < 4; r++) {
        float x = sc[cg][r] * 0.125f;
        if (CAUSAL && kt == qt) {   // wave-uniform branch; mask future keys
          const int key = kb + cg * 16 + g * 4 + r;
          if (key > qi) x = -1e9f;
        }
        v4[cg][r] = x;
      }

    // row max: 16 in-register + 2 cross-group shfls
    float mx = v4[0][0];
    #pragma unroll
    for (int cg = 0; cg < 4; cg++)
      #pragma unroll
      for (int r = 0; r < 4; r++) mx = fmaxf(mx, v4[cg][r]);
    mx = fmaxf(mx, __shfl_xor(mx, 16));
    mx = fmaxf(mx, __shfl_xor(mx, 32));
    const float mn = fmaxf(mrow, mx);
    const float alpha = __expf(mrow - mn);
    mrow = mn;

    float rs = 0.f;
    #pragma unroll
    for (int cg = 0; cg < 4; cg++)
      #pragma unroll
      for (int r = 0; r < 4; r++) { v4[cg][r] = __expf(v4[cg][r] - mn); rs += v4[cg][r]; }
    rs += __shfl_xor(rs, 16);
    rs += __shfl_xor(rs, 32);
    lrow = lrow * alpha + rs;

    // rescale O: alpha for q = g*4+r lives in lane g*4+r (lanes 0-15 cover all q)
    #pragma unroll
    for (int r = 0; r < 4; r++) {
      const float aR = __shfl(alpha, (g << 2) | r);
      #pragma unroll
      for (int dt = 0; dt < 4; dt++) oacc[dt][r] *= aR;
    }

    // P^T -> P in LDS: pair index p = 8*cg + 2*g + b holds keys 2p, 2p+1
    char* pbase = (char*)&Ps[w][0];
    #pragma unroll
    for (int cg = 0; cg < 4; cg++) {
      const uint32_t p0 = (uint32_t)(uint16_t)f2bf(v4[cg][0]) |
                          ((uint32_t)(uint16_t)f2bf(v4[cg][1]) << 16);
      const uint32_t p1 = (uint32_t)(uint16_t)f2bf(v4[cg][2]) |
                          ((uint32_t)(uint16_t)f2bf(v4[cg][3]) << 16);
      *(uint32_t*)(pbase + swzb(m16, (8 * cg + 2 * g) * 4))     = p0;
      *(uint32_t*)(pbase + swzb(m16, (8 * cg + 2 * g + 1) * 4)) = p1;
    }

    // P write -> P read is same-wave only (Ps is per-wave): lgkm drain, no barrier.
    asm volatile("s_waitcnt lgkmcnt(0)" ::: "memory");
    __builtin_amdgcn_sched_barrier(0);

    // PV: P (A-op, row=q=m16) x V (B-op), k = 64 keys as 2 chains
    const short8 pf0 = *(const short8*)(pbase + swzb(m16, 16 * g));
    const short8 pf1 = *(const short8*)(pbase + swzb(m16, 64 + 16 * g));
    const char* vsrc = (const char*)&VT[cur][0];
    #pragma unroll
    for (int dt = 0; dt < 4; dt++) {
      const short8 vfa = *(const short8*)(vsrc + swzb(dt * 16 + m16, 16 * g));
      const short8 vfb = *(const short8*)(vsrc + swzb(dt * 16 + m16, 64 + 16 * g));
      oacc[dt] = __builtin_amdgcn_mfma_f32_16x16x32_bf16(pf0, vfa, oacc[dt], 0, 0, 0);
      oacc[dt] = __builtin_amdgcn_mfma_f32_16x16x32_bf16(pf1, vfb, oacc[dt], 0, 0, 0);
    }

    // write prefetched tile into the other buffer; single barrier per tile.
    // (buf cur^1 was last read in iter kt-1; that iter's barrier fenced those reads)
    if (more) {
      char* kd = (char*)&Ks[cur ^ 1][0];
      *(short8*)(kd + swzb(kr, kc * 2))      = kst0;
      *(short8*)(kd + swzb(kr, kc * 2 + 16)) = kst1;
      char* vd = (char*)&VT[cur ^ 1][0];
      #pragma unroll
      for (int j = 0; j < 8; j++) {
        const uint32_t pk = (uint32_t)(uint16_t)vst0[j] | ((uint32_t)(uint16_t)vst1[j] << 16);
        *(uint32_t*)(vd + swzb(vcg + j, vkp * 2)) = pk;
      }
      __syncthreads();
    }
  }

  // epilogue: O row = q = g*4+r; l for that q lives in lane g*4+r
  float lR[4];
  #pragma unroll
  for (int r = 0; r < 4; r++) lR[r] = __shfl(lrow, (g << 2) | r);
  #pragma unroll
  for (int dt = 0; dt < 4; dt++)
    #pragma unroll
    for (int r = 0; r < 4; r++) {
      const size_t orow = (size_t)(rowQ + wrow + g * 4 + r);
      Op[orow * ldo + h * 64 + dt * 16 + m16] = f2bf(oacc[dt][r] / lR[r]);
    }
}

// ---------- LayerNorm over D=1024; FINAL=1 stores fp32 ----------
template<int FINAL>
__global__ __launch_bounds__(256)
void layernorm_bf16(const short* __restrict__ x, const short* __restrict__ gamma,
                    const short* __restrict__ beta, void* __restrict__ out)
{
  const int D = 1024;
  const int row = blockIdx.x, tid = threadIdx.x;
  const short* xr = x + (size_t)row * D;
  short4v xv = *(const short4v*)(xr + tid * 4);
  float v[4], s = 0.f, ss = 0.f;
  #pragma unroll
  for (int j = 0; j < 4; j++) { v[j] = bf2f(xv[j]); s += v[j]; ss += v[j] * v[j]; }
  #pragma unroll
  for (int off = 32; off; off >>= 1) { s += __shfl_xor(s, off); ss += __shfl_xor(ss, off); }
  __shared__ float red[8];
  const int w = tid >> 6, lane = tid & 63;
  if (lane == 0) { red[w] = s; red[4 + w] = ss; }
  __syncthreads();
  s  = red[0] + red[1] + red[2] + red[3];
  ss = red[4] + red[5] + red[6] + red[7];
  const float mean = s * (1.f / D);
  const float var  = ss * (1.f / D) - mean * mean;
  const float inv  = rsqrtf(var + 1e-3f);
  float o[4];
  #pragma unroll
  for (int j = 0; j < 4; j++)
    o[j] = (v[j] - mean) * inv * bf2f(gamma[tid * 4 + j]) + bf2f(beta[tid * 4 + j]);
  if (FINAL) {
    floatx4 ov;
    #pragma unroll
    for (int j = 0; j < 4; j++) ov[j] = o[j];
    *(floatx4*)((float*)out + (size_t)row * D + tid * 4) = ov;
  } else {
    short4v ov;
    #pragma unroll
    for (int j = 0; j < 4; j++) ov[j] = f2bf(o[j]);
    *(short4v*)((short*)out + (size_t)row * D + tid * 4) = ov;
  }
}

// ---------- host ----------
extern "C" void kernel_launch(void* const* d_in, const int* in_sizes, int n_in,
                              void* d_out, int out_size, void* d_ws, size_t ws_size,
                              hipStream_t stream) {
  (void)in_sizes; (void)n_in; (void)out_size; (void)ws_size;
  const int M = 4096;
  const size_t MM = 1024 * 1024;

  short* ws = (short*)d_ws;
  short* wt_qkv1 = ws;                   // [3072][1024]
  short* wt_o1   = wt_qkv1 + 3 * MM;
  short* wt_q2   = wt_o1 + MM;
  short* wt_kv2  = wt_q2 + MM;           // [2048][1024]
  short* wt_o2   = wt_kv2 + 2 * MM;
  short* wt_ff1  = wt_o2 + MM;           // [4096][1024]
  short* wt_ff2  = wt_ff1 + 4 * MM;      // [1024][4096]
  short* P       = ws + 16 * MM;         // 19456 param shorts
  short* encc    = ws + 16 * MM + 32768; // 4M enc bf16
  short* act0    = encc + 4 * MM;        // 16M: qkv1 | kv2+q2 | ffn-hidden
  short* attn    = act0 + 16 * MM;       // 4M
  short* t1      = attn + 4 * MM;        // 4M
  short* t2      = t1 + 4 * MM;          // 4M; xc aliases t2 (dead before t2 written)
  short* xc      = t2;

  short* bqkv1 = P,        *bo1  = P + 3072, *bkv2 = P + 4096, *bq2 = P + 6144;
  short* bo2   = P + 7168, *bff1 = P + 8192, *bff2 = P + 12288;
  short* g1 = P + 13312, *be1 = P + 14336, *g2 = P + 15360, *be2 = P + 16384;
  short* g3 = P + 17408, *be3 = P + 18432;

  // 1) merged preprocessing: params | x/enc convert | 10 weight transposes (1 launch)
  PreArgs pa;
  const int srcidx[19] = {6, 7, 8, 9, 15, 16, 14, 17, 19, 19, 19, 19, 21, 22, 23, 24, 25, 26, 27};
  const int offs[19]   = {0, 0, 0, 0, 0,  0,  0,  0,  0, 1024, 2048, 3072, 0, 0, 0, 0, 0, 0, 0};
  for (int i = 0; i < 19; i++) { pa.ps[i] = (const float*)d_in[srcidx[i]]; pa.poff[i] = offs[i]; }
  pa.pdst = P;
  pa.x = (const float*)d_in[0]; pa.enc = (const float*)d_in[1];
  pa.xc = xc; pa.encc = encc;
  const int widx[10] = {2, 3, 4, 5, 10, 11, 12, 13, 18, 20};
  short* wdst[10] = {wt_qkv1, wt_qkv1 + MM, wt_qkv1 + 2 * MM, wt_o1, wt_q2,
                     wt_kv2, wt_kv2 + MM, wt_o2, wt_ff1, wt_ff2};
  const int wK[10] = {1024, 1024, 1024, 1024, 1024, 1024, 1024, 1024, 1024, 4096};
  const int wN[10] = {1024, 1024, 1024, 1024, 1024, 1024, 1024, 1024, 4096, 1024};
  int base = 0;
  for (int i = 0; i < 10; i++) {
    pa.tsrc[i] = (const float*)d_in[widx[i]];
    pa.tdst[i] = wdst[i];
    pa.tK[i] = wK[i]; pa.tN[i] = wN[i]; pa.tbase[i] = base;
    base += (wN[i] / 32) * (wK[i] / 32);
  }
  preprocess<<<19 + 8192 + base, 256, 0, stream>>>(pa);   // base = 16384

  // 2) self-attention block
  short* qkv1 = act0;  // [4096][3072]
  gemm_bt<0, 0, 128, 128><<<dim3((M / 128) * (3072 / 128)), 256, 0, stream>>>(
      xc, wt_qkv1, bqkv1, nullptr, qkv1, M, 3072, 1024);
  attention<1><<<dim3(1024), 256, 0, stream>>>(
      qkv1, 3072, qkv1 + 1024, 3072, qkv1 + 2048, 3072, attn, 1024);
  gemm_bt64<0, 1><<<dim3((M / 64) * (1024 / 64)), 256, 0, stream>>>(
      attn, wt_o1, bo1, xc, t1, M, 1024, 1024);
  layernorm_bf16<0><<<dim3(4096), 256, 0, stream>>>(t1, g1, be1, t1);  // o1 in place

  // 3) cross-attention block
  short* kv2 = act0;            // [4096][2048]
  short* q2  = act0 + 8 * MM;   // [4096][1024]
  gemm_bt<0, 0, 64, 128><<<dim3((M / 64) * (2048 / 128)), 256, 0, stream>>>(
      encc, wt_kv2, bkv2, nullptr, kv2, M, 2048, 1024);
  gemm_bt64<0, 0><<<dim3((M / 64) * (1024 / 64)), 256, 0, stream>>>(
      t1, wt_q2, bq2, nullptr, q2, M, 1024, 1024);
  attention<0><<<dim3(1024), 256, 0, stream>>>(
      q2, 1024, kv2, 2048, kv2 + 1024, 2048, attn, 1024);
  gemm_bt64<0, 1><<<dim3((M / 64) * (1024 / 64)), 256, 0, stream>>>(
      attn, wt_o2, bo2, t1, t2, M, 1024, 1024);
  layernorm_bf16<0><<<dim3(4096), 256, 0, stream>>>(t2, g2, be2, t2);  // o2 in place

  // 4) FFN block
  short* hidden = act0;  // [4096][4096]
  gemm_bt<1, 0, 128, 128><<<dim3((M / 128) * (4096 / 128)), 256, 0, stream>>>(
      t2, wt_ff1, bff1, nullptr, hidden, M, 4096, 1024);
  gemm_bt64<0, 1><<<dim3((M / 64) * (1024 / 64)), 256, 0, stream>>>(
      hidden, wt_ff2, bff2, t2, attn, M, 1024, 4096);
  layernorm_bf16<1><<<dim3(4096), 256, 0, stream>>>(attn, g3, be3, d_out);
}